// Round 1
// baseline (297.895 us; speedup 1.0000x reference)
//
#include <hip/hip_runtime.h>

// AnchorGenerator: output (H*W*3*3, 4) fp32 anchors, H=W=512, BASE=16.
// Pure write-only kernel: input feature_map values are never used (only its
// static shape). 37.75 MB of writes -> memory-bound on store bandwidth.

#define AG_H 512
#define AG_W 512
#define AG_N (AG_H * AG_W * 9)   // 2,359,296 anchors

__global__ __launch_bounds__(256) void
AnchorGenerator_89919435309502_kernel(float4* __restrict__ out) {
    int t = blockIdx.x * 256 + threadIdx.x;
    if (t >= AG_N) return;

    // t = ((y*W + x)*3 + s)*3 + r
    unsigned ut  = (unsigned)t;
    unsigned pix = ut / 9u;            // magic-mul, no HW divide
    unsigned sr  = ut - pix * 9u;
    unsigned s   = sr / 3u;
    unsigned r   = sr - s * 3u;
    unsigned x   = pix & (AG_W - 1);
    unsigned y   = pix >> 9;           // W = 512 = 2^9

    float xc = (float)x * 16.0f + 8.0f;
    float yc = (float)y * 16.0f + 8.0f;

    // scale in {0.5,1,2} -> 8*scale = 4<<s exactly.
    // ratio in {0.5,1,2} -> sqrt_r = sqrtf(0.5f * (1<<r)).
    // hw = (16*scale*sqrt_r)/2 == (8*scale)*sqrt_r  (exact pow2 scaling)
    // hh = (16*scale/sqrt_r)/2 == (8*scale)/sqrt_r
    float half8 = (float)(4 << s);
    float sq    = sqrtf(0.5f * (float)(1u << r));
    float hw    = half8 * sq;
    float hh    = half8 / sq;

    const float xmax = (float)(AG_W * 16);  // 8192
    const float ymax = (float)(AG_H * 16);  // 8192

    float x1 = fmaxf(xc - hw, 0.0f);
    float y1 = fmaxf(yc - hh, 0.0f);
    float x2 = fminf(xc + hw, xmax);
    float y2 = fminf(yc + hh, ymax);

    out[t] = make_float4(x1, y1, x2, y2);
}

extern "C" void kernel_launch(void* const* d_in, const int* in_sizes, int n_in,
                              void* d_out, int out_size, void* d_ws, size_t ws_size,
                              hipStream_t stream) {
    (void)d_in; (void)in_sizes; (void)n_in; (void)d_ws; (void)ws_size;
    (void)out_size;
    float4* out = (float4*)d_out;
    int blocks = AG_N / 256;  // 9216, exact
    AnchorGenerator_89919435309502_kernel<<<blocks, 256, 0, stream>>>(out);
}